// Round 9
// baseline (227.363 us; speedup 1.0000x reference)
//
#include <hip/hip_runtime.h>
#include <hip/hip_bf16.h>

#define CHN 512
#define TLEN 2048
#define KSZ 5
#define BATCH 16

typedef __hip_bfloat16 bf16;
typedef short bf16x8 __attribute__((ext_vector_type(8)));   // 8 bf16 (4 VGPRs)
typedef float f32x4  __attribute__((ext_vector_type(4)));

// ws layout:
//   samp : float2[B*T*5]  (pos, sig)       =  1,310,720 B
//   w1t  : bf16 [16][4][3][64][40]         =    983,040 B   (pre-tiled W1)
//   wpk  : float[512][32]                  =     65,536 B   (packed ow+mw)
//   dtile: bf16 [B][16][2050][32]          = 33,587,200 B   (bf16 def, k2-tiled)
//          row t+1 holds def[b][ch*32+col][t]; rows 0,2049 = zeros (halo)
#define SAMP_BYTES (BATCH*TLEN*KSZ*8)
#define W1T_ELEMS  (16*4*3*64*40)
#define W1T_BYTES  (W1T_ELEMS*2)
#define WPK_BYTES  65536
#define DT_ROWS    2050
#define DT_CHUNK   (DT_ROWS*32)                 // elems per (b,ch)
#define DT_BYTES   ((size_t)BATCH*16*DT_CHUNK*2)

// ---------------------------------------------------------------------------
// kPrep: fused kP (w1 retile) + kW (ow/mw pack) + kZ (outs = b2) +
//        dtile halo-row zeroing. One dispatch.
// ---------------------------------------------------------------------------
__global__ __launch_bounds__(256) void kPrep(const float* __restrict__ w1,
    bf16* __restrict__ w1t, const float* __restrict__ ow,
    const float* __restrict__ mw, float* __restrict__ wpk,
    float* __restrict__ outs, const float* __restrict__ b2p,
    bf16* __restrict__ dt)
{
  int bx = blockIdx.x;
  int tidl = threadIdx.x;
  const int NP = W1T_ELEMS/256;                // 1920
  if (bx < NP) {
    // kP: w1 fp32 [co][ci][r] -> w1t bf16 [ch][q][r][row][40], co = q*64+row
    int idx  = bx*256 + tidl;                  // < 491520
    int c40  = idx % 40;
    int rest = idx / 40;
    int row  = rest & 63;
    int rr   = rest >> 6;          // (ch*4+q)*3 + r
    int r    = rr % 3;
    int cq   = rr / 3;             // ch*4 + q
    int q    = cq & 3;
    int ch   = cq >> 2;
    int co   = q*64 + row;
    float v = 0.f;
    if (c40 < 32) v = w1[(size_t)co*(CHN*3) + (ch*32 + c40)*3 + r];
    w1t[idx] = __float2bfloat16(v);
  } else if (bx < NP + 64) {
    // kW: pack ow/mw -> wpk[c][32]
    int idx = (bx - NP)*256 + tidl;            // < 16384
    int j = idx & 31, c = idx >> 5;
    float v = 0.f;
    if (j < 15)      { int o = j/3,  d = j - o*3;  v = ow[o*(CHN*3) + c*3 + d]; }
    else if (j < 30) { int jj = j-15; int o = jj/3, d = jj - o*3;
                       v = mw[o*(CHN*3) + c*3 + d]; }
    wpk[idx] = v;
  } else if (bx < NP + 192) {
    // kZ: outs = b2 (k2 blocks atomically accumulate on top)
    outs[(bx - NP - 64)*256 + tidl] = b2p[0];
  } else if (dt) {
    // zero dtile halo rows 0 (t=-1) and 2049 (t=2048), all 256 (b,ch) chunks
    int z = (bx - NP - 192)*256 + tidl;        // < 16384
    int chunk = z >> 6;                        // 0..255
    int row   = ((z >> 5) & 1) ? (DT_ROWS-1) : 0;
    int col   = z & 31;
    dt[(size_t)chunk*DT_CHUNK + row*32 + col] = __float2bfloat16(0.f);
  }
}

// ---------------------------------------------------------------------------
// kS: offset conv (out 0..4) + modulator conv (+sigmoid) -> sampling params.
// grid (TLEN/64, B), block (64 t, 8 cg). Each thread reduces 64 channels.
// samp[b,t,k] = (pos, sig); kDf re-derives base/wf/wc (bitwise-identical).
// ---------------------------------------------------------------------------
__global__ __launch_bounds__(512) void kS(const float* __restrict__ x,
    const float* __restrict__ wpk, const float* __restrict__ ob,
    const float* __restrict__ mb, float2* __restrict__ samp)
{
  int b  = blockIdx.y;
  int t0 = blockIdx.x*64;
  int tx = threadIdx.x;
  int cg = threadIdx.y;            // 0..7 (wave-uniform: wave = one tx row)
  int t  = t0 + tx;

  __shared__ float red[8][64][10];

  float acc[10];
  #pragma unroll
  for (int i=0;i<10;++i) acc[i]=0.f;
  const float* xb = x + (size_t)b*CHN*TLEN;
  int c0 = cg*64;
  #pragma unroll 4
  for (int c=c0;c<c0+64;++c) {
    int cu = __builtin_amdgcn_readfirstlane(c);
    const float* wp = wpk + cu*32;             // scalar -> s_load_dwordx8
    const float* xr = xb + (size_t)cu*TLEN;
    float xm = (t>0)      ? xr[t-1] : 0.f;
    float xc = xr[t];
    float xp = (t<TLEN-1) ? xr[t+1] : 0.f;
    #pragma unroll
    for (int o=0;o<5;++o) {
      acc[o]   = fmaf(xm, wp[o*3+0],    acc[o]);
      acc[o]   = fmaf(xc, wp[o*3+1],    acc[o]);
      acc[o]   = fmaf(xp, wp[o*3+2],    acc[o]);
      acc[5+o] = fmaf(xm, wp[15+o*3+0], acc[5+o]);
      acc[5+o] = fmaf(xc, wp[15+o*3+1], acc[5+o]);
      acc[5+o] = fmaf(xp, wp[15+o*3+2], acc[5+o]);
    }
  }
  #pragma unroll
  for (int i=0;i<10;++i) red[cg][tx][i] = acc[i];
  __syncthreads();
  for (int s=4;s>0;s>>=1) {
    if (cg < s) {
      #pragma unroll
      for (int i=0;i<10;++i) red[cg][tx][i] += red[cg+s][tx][i];
    }
    __syncthreads();
  }
  if (cg==0) {
    #pragma unroll
    for (int k=0;k<KSZ;++k) {
      float off = red[0][tx][k]   + ob[k];
      float mv  = red[0][tx][5+k] + mb[k];
      float sig = 1.f/(1.f + expf(-mv));
      float pos = (float)(t + k - 2) + off;
      pos = fminf(fmaxf(pos, 0.f), (float)(TLEN-1));
      samp[((size_t)b*TLEN + t)*KSZ + k] = make_float2(pos, sig);
    }
  }
}

// ---------------------------------------------------------------------------
// kDf: deformable sampling w/ diagonal weight — wave-synchronous, NO barrier,
// 2-tile software pipeline with COUNTED vmcnt (T4): per wave, issue sampg
// loads FIRST, then DMA tile A, then DMA tile B (clean vmcnt ordering).
// Compute params for both tiles (compiler's wait drains only sampg) ->
// s_waitcnt vmcnt(10) (waits A; B stays in flight) -> compute+store A ->
// s_waitcnt vmcnt(0) (B landed under A's ~1500-cy compute) -> compute+store B.
// grid (T/256, C/16, B), block = ONE wave (64 thr). LDS 2x10.25 KB.
// Thread owns t = tA + j*64 + tx, j=0..3 (A: j<2, B: j>=2) x 16 c-rows.
// Wave-uniform fallback to global gathers if any base escapes the halo.
// ---------------------------------------------------------------------------
#define BT   128
#define HALO 16
#define XLEN 160   // BT + 2*HALO

template<bool WDT>
__global__ __launch_bounds__(64) void kDf(const float* __restrict__ x,
    const float* __restrict__ wgt, const float2* __restrict__ sampg,
    float* __restrict__ out, bf16* __restrict__ dt)
{
  int b  = blockIdx.z;
  int c0 = blockIdx.y*16;
  int tA = blockIdx.x*(2*BT);
  int tB = tA + BT;
  int tx = threadIdx.x;

  __shared__ float xs[2][16*XLEN];  // 20,480 B

  int loA = min(max(tA - HALO, 0), TLEN - XLEN);  // windows always in-bounds,
  int loB = min(max(tB - HALO, 0), TLEN - XLEN);  // 16B-aligned (lo%16==0)

  // --- 1: sampg loads FIRST (so DMA fences count cleanly: sampg < A < B)
  float2 sv[4][KSZ];
  #pragma unroll
  for (int j=0;j<4;++j)
    #pragma unroll
    for (int k=0;k<KSZ;++k)
      sv[j][k] = sampg[((size_t)b*TLEN + tA + j*64 + tx)*KSZ + k];
  __builtin_amdgcn_sched_barrier(0);

  // --- 2: DMA tile A (10 insts), then tile B (10 insts)
  const float* xb = x + (size_t)b*CHN*TLEN;
  #pragma unroll
  for (int it = 0; it < 10; ++it) {
    int idx = tx + it*64;
    int c  = idx / 40, c4 = idx - c*40;
    __builtin_amdgcn_global_load_lds(
        (const __attribute__((address_space(1))) unsigned int*)
          (xb + (size_t)(c0 + c)*TLEN + loA + c4*4),
        (__attribute__((address_space(3))) unsigned int*)&xs[0][idx*4],
        16, 0, 0);
  }
  #pragma unroll
  for (int it = 0; it < 10; ++it) {
    int idx = tx + it*64;
    int c  = idx / 40, c4 = idx - c*40;
    __builtin_amdgcn_global_load_lds(
        (const __attribute__((address_space(1))) unsigned int*)
          (xb + (size_t)(c0 + c)*TLEN + loB + c4*4),
        (__attribute__((address_space(3))) unsigned int*)&xs[1][idx*4],
        16, 0, 0);
  }

  // --- 3: params for all 4 j (consumes sampg; DMAs remain outstanding)
  int   bl[4][KSZ];
  float wf[4][KSZ], wc[4][KSZ];
  bool ok = true;
  #pragma unroll
  for (int j=0;j<4;++j) {
    int lo = (j<2) ? loA : loB;
    #pragma unroll
    for (int k=0;k<KSZ;++k) {
      float pos = sv[j][k].x, sig = sv[j][k].y;
      float pf = floorf(pos), pc = ceilf(pos);
      int base = min((int)pf, TLEN-2);
      wf[j][k] = (pc - pos)*sig;     // ref quirk: pos integral -> wf=wc=0
      wc[j][k] = (pos - pf)*sig;
      int bloc = base - lo;
      bl[j][k] = bloc;
      ok = ok && (bloc >= 0) && (bloc <= XLEN-2);
    }
  }
  int fast = __all((int)ok);        // wave-uniform branch

  if (fast) {
    // --- fence A: wait the oldest 10 VMEM (= DMA A); B stays in flight
    asm volatile("s_waitcnt vmcnt(10)" ::: "memory");
    __builtin_amdgcn_sched_barrier(0);

    unsigned pk0[8], pk1[8];
    #pragma unroll
    for (int i=0;i<16;++i) {         // ---- tile A (j=0,1) ----
      int cu = __builtin_amdgcn_readfirstlane(c0 + i);
      const float* wd = wgt + (size_t)cu*(CHN*KSZ) + (size_t)cu*KSZ;  // diag
      float w0 = wd[0], w1v = wd[1], w2v = wd[2], w3 = wd[3], w4 = wd[4];
      const float* xr = &xs[0][i*XLEN];
      float o0, o1;
      {
        float a = 0.f;
        a = fmaf(fmaf(xr[bl[0][0]+1], wc[0][0], xr[bl[0][0]]*wf[0][0]), w0,  a);
        a = fmaf(fmaf(xr[bl[0][1]+1], wc[0][1], xr[bl[0][1]]*wf[0][1]), w1v, a);
        a = fmaf(fmaf(xr[bl[0][2]+1], wc[0][2], xr[bl[0][2]]*wf[0][2]), w2v, a);
        a = fmaf(fmaf(xr[bl[0][3]+1], wc[0][3], xr[bl[0][3]]*wf[0][3]), w3,  a);
        a = fmaf(fmaf(xr[bl[0][4]+1], wc[0][4], xr[bl[0][4]]*wf[0][4]), w4,  a);
        o0 = a;
      }
      {
        float a = 0.f;
        a = fmaf(fmaf(xr[bl[1][0]+1], wc[1][0], xr[bl[1][0]]*wf[1][0]), w0,  a);
        a = fmaf(fmaf(xr[bl[1][1]+1], wc[1][1], xr[bl[1][1]]*wf[1][1]), w1v, a);
        a = fmaf(fmaf(xr[bl[1][2]+1], wc[1][2], xr[bl[1][2]]*wf[1][2]), w2v, a);
        a = fmaf(fmaf(xr[bl[1][3]+1], wc[1][3], xr[bl[1][3]]*wf[1][3]), w3,  a);
        a = fmaf(fmaf(xr[bl[1][4]+1], wc[1][4], xr[bl[1][4]]*wf[1][4]), w4,  a);
        o1 = a;
      }
      size_t op = ((size_t)b*CHN + cu)*TLEN + tA + tx;
      out[op]      = o0;
      out[op + 64] = o1;
      if (WDT) {
        union { bf16 h; unsigned short u; } cv0, cv1;
        cv0.h = __float2bfloat16(o0);
        cv1.h = __float2bfloat16(o1);
        if (i & 1) { pk0[i>>1] |= (unsigned)cv0.u << 16;
                     pk1[i>>1] |= (unsigned)cv1.u << 16; }
        else       { pk0[i>>1]  = cv0.u;  pk1[i>>1]  = cv1.u; }
      }
    }
    int ch, colb;
    if (WDT) {
      ch   = blockIdx.y >> 1;
      colb = (blockIdx.y & 1)*16;
      bf16* p0 = dt + (size_t)(b*16 + ch)*DT_CHUNK
                    + (size_t)(tA + tx + 1)*32 + colb;
      *(uint4*)p0       = make_uint4(pk0[0], pk0[1], pk0[2], pk0[3]);
      *((uint4*)p0 + 1) = make_uint4(pk0[4], pk0[5], pk0[6], pk0[7]);
      bf16* p1 = p0 + 64*32;
      *(uint4*)p1       = make_uint4(pk1[0], pk1[1], pk1[2], pk1[3]);
      *((uint4*)p1 + 1) = make_uint4(pk1[4], pk1[5], pk1[6], pk1[7]);
    }

    // --- fence B: all VMEM (DMA B landed under tile A's compute)
    asm volatile("s_waitcnt vmcnt(0)" ::: "memory");
    __builtin_amdgcn_sched_barrier(0);

    #pragma unroll
    for (int i=0;i<16;++i) {         // ---- tile B (j=2,3) ----
      int cu = __builtin_amdgcn_readfirstlane(c0 + i);
      const float* wd = wgt + (size_t)cu*(CHN*KSZ) + (size_t)cu*KSZ;
      float w0 = wd[0], w1v = wd[1], w2v = wd[2], w3 = wd[3], w4 = wd[4];
      const float* xr = &xs[1][i*XLEN];
      float o0, o1;
      {
        float a = 0.f;
        a = fmaf(fmaf(xr[bl[2][0]+1], wc[2][0], xr[bl[2][0]]*wf[2][0]), w0,  a);
        a = fmaf(fmaf(xr[bl[2][1]+1], wc[2][1], xr[bl[2][1]]*wf[2][1]), w1v, a);
        a = fmaf(fmaf(xr[bl[2][2]+1], wc[2][2], xr[bl[2][2]]*wf[2][2]), w2v, a);
        a = fmaf(fmaf(xr[bl[2][3]+1], wc[2][3], xr[bl[2][3]]*wf[2][3]), w3,  a);
        a = fmaf(fmaf(xr[bl[2][4]+1], wc[2][4], xr[bl[2][4]]*wf[2][4]), w4,  a);
        o0 = a;
      }
      {
        float a = 0.f;
        a = fmaf(fmaf(xr[bl[3][0]+1], wc[3][0], xr[bl[3][0]]*wf[3][0]), w0,  a);
        a = fmaf(fmaf(xr[bl[3][1]+1], wc[3][1], xr[bl[3][1]]*wf[3][1]), w1v, a);
        a = fmaf(fmaf(xr[bl[3][2]+1], wc[3][2], xr[bl[3][2]]*wf[3][2]), w2v, a);
        a = fmaf(fmaf(xr[bl[3][3]+1], wc[3][3], xr[bl[3][3]]*wf[3][3]), w3,  a);
        a = fmaf(fmaf(xr[bl[3][4]+1], wc[3][4], xr[bl[3][4]]*wf[3][4]), w4,  a);
        o1 = a;
      }
      size_t op = ((size_t)b*CHN + cu)*TLEN + tB + tx;
      out[op]      = o0;
      out[op + 64] = o1;
      if (WDT) {
        union { bf16 h; unsigned short u; } cv0, cv1;
        cv0.h = __float2bfloat16(o0);
        cv1.h = __float2bfloat16(o1);
        if (i & 1) { pk0[i>>1] |= (unsigned)cv0.u << 16;
                     pk1[i>>1] |= (unsigned)cv1.u << 16; }
        else       { pk0[i>>1]  = cv0.u;  pk1[i>>1]  = cv1.u; }
      }
    }
    if (WDT) {
      bf16* p0 = dt + (size_t)(b*16 + ch)*DT_CHUNK
                    + (size_t)(tB + tx + 1)*32 + colb;
      *(uint4*)p0       = make_uint4(pk0[0], pk0[1], pk0[2], pk0[3]);
      *((uint4*)p0 + 1) = make_uint4(pk0[4], pk0[5], pk0[6], pk0[7]);
      bf16* p1 = p0 + 64*32;
      *(uint4*)p1       = make_uint4(pk1[0], pk1[1], pk1[2], pk1[3]);
      *((uint4*)p1 + 1) = make_uint4(pk1[4], pk1[5], pk1[6], pk1[7]);
    }
  } else {
    // slow path (never taken with bench weights): global gathers, same math
    asm volatile("s_waitcnt vmcnt(0)" ::: "memory");
    __builtin_amdgcn_sched_barrier(0);
    unsigned pk0[8], pk1[8];
    #pragma unroll
    for (int jj=0;jj<2;++jj) {       // jj=0: tile A, jj=1: tile B
      int tb = (jj==0) ? tA : tB;
      int lo = (jj==0) ? loA : loB;
      #pragma unroll
      for (int i=0;i<16;++i) {
        int cu = __builtin_amdgcn_readfirstlane(c0 + i);
        const float* wd = wgt + (size_t)cu*(CHN*KSZ) + (size_t)cu*KSZ;
        float wk0 = wd[0], wk1 = wd[1], wk2 = wd[2], wk3 = wd[3], wk4 = wd[4];
        const float* xr = xb + (size_t)cu*TLEN + lo;   // xr[bl] == x[base]
        float o[2];
        #pragma unroll
        for (int j2=0;j2<2;++j2) {
          int j = jj*2 + j2;
          float a = 0.f;
          a = fmaf(fmaf(xr[bl[j][0]+1], wc[j][0], xr[bl[j][0]]*wf[j][0]), wk0, a);
          a = fmaf(fmaf(xr[bl[j][1]+1], wc[j][1], xr[bl[j][1]]*wf[j][1]), wk1, a);
          a = fmaf(fmaf(xr[bl[j][2]+1], wc[j][2], xr[bl[j][2]]*wf[j][2]), wk2, a);
          a = fmaf(fmaf(xr[bl[j][3]+1], wc[j][3], xr[bl[j][3]]*wf[j][3]), wk3, a);
          a = fmaf(fmaf(xr[bl[j][4]+1], wc[j][4], xr[bl[j][4]]*wf[j][4]), wk4, a);
          o[j2] = a;
        }
        size_t op = ((size_t)b*CHN + cu)*TLEN + tb + tx;
        out[op]      = o[0];
        out[op + 64] = o[1];
        if (WDT) {
          union { bf16 h; unsigned short u; } cv0, cv1;
          cv0.h = __float2bfloat16(o[0]);
          cv1.h = __float2bfloat16(o[1]);
          if (i & 1) { pk0[i>>1] |= (unsigned)cv0.u << 16;
                       pk1[i>>1] |= (unsigned)cv1.u << 16; }
          else       { pk0[i>>1]  = cv0.u;  pk1[i>>1]  = cv1.u; }
        }
      }
      if (WDT) {
        int ch   = blockIdx.y >> 1;
        int colb = (blockIdx.y & 1)*16;
        bf16* p0 = dt + (size_t)(b*16 + ch)*DT_CHUNK
                      + (size_t)(tb + tx + 1)*32 + colb;
        *(uint4*)p0       = make_uint4(pk0[0], pk0[1], pk0[2], pk0[3]);
        *((uint4*)p0 + 1) = make_uint4(pk0[4], pk0[5], pk0[6], pk0[7]);
        bf16* p1 = p0 + 64*32;
        *(uint4*)p1       = make_uint4(pk1[0], pk1[1], pk1[2], pk1[3]);
        *((uint4*)p1 + 1) = make_uint4(pk1[4], pk1[5], pk1[6], pk1[7]);
      }
    }
  }
}

// ---------------------------------------------------------------------------
// k2d: fused rp1(conv3, 512->256)+ReLU+rp2(256->1)+bias, bf16 MFMA.
// BOTH operands staged by pure global_load_lds DMA (Ws from w1t, Dt from
// dtile -- no loads/cvt/ds_write in the loop). Double-buffered, 2 blocks/CU
// (LDS 64.8 KB). BM=64 (co-quarter, grid y=4), BN=256, 256 thr (4 waves).
// Per iter: issue next Ws+Dt DMA -> COMPUTE(cur) hides DMA latency ->
// single barrier. Partial co-sums atomicAdd into outs (pre-set to b2).
// ---------------------------------------------------------------------------
#define DMA_W2(dst, ch_) do {                                                  \
  const char* gs = (const char*)(w1t + (size_t)((ch_)*4 + m0)*7680);           \
  char* ld = (char*)&Ws[dst][0];                                               \
  for (int of = tid*16; of < 15360; of += 4096) {                              \
    __builtin_amdgcn_global_load_lds(                                          \
        (const __attribute__((address_space(1))) unsigned int*)(gs + of),      \
        (__attribute__((address_space(3))) unsigned int*)(ld + of), 16, 0, 0); \
  }                                                                            \
} while(0)

#define DMA_D2(dst, ch_) do {                                                  \
  const char* gs = (const char*)(dt + (size_t)(b*16 + (ch_))*DT_CHUNK          \
                                    + (size_t)t0*32);                          \
  char* ld = (char*)&Dt[dst][0];                                               \
  for (int of = tid*16; of < 16512; of += 4096) {                              \
    __builtin_amdgcn_global_load_lds(                                          \
        (const __attribute__((address_space(1))) unsigned int*)(gs + of),      \
        (__attribute__((address_space(3))) unsigned int*)(ld + of), 16, 0, 0); \
  }                                                                            \
} while(0)

#define COMPUTE2(cur) do {                                                     \
  _Pragma("unroll")                                                            \
  for (int r=0;r<3;++r) {                                                      \
    bf16x8 af[4], bfr[4];                                                      \
    _Pragma("unroll")                                                          \
    for (int mt=0;mt<4;++mt)                                                   \
      af[mt] = *(const bf16x8*)&Ws[cur][(size_t)(r*64 + mt*16 + ln15)*40 + quad*8];\
    _Pragma("unroll")                                                          \
    for (int nt=0;nt<4;++nt)                                                   \
      bfr[nt] = *(const bf16x8*)&Dt[cur][(size_t)(wN*64 + nt*16 + ln15 + r)*32 + quad*8];\
    _Pragma("unroll")                                                          \
    for (int mt=0;mt<4;++mt)                                                   \
      _Pragma("unroll")                                                        \
      for (int nt=0;nt<4;++nt)                                                 \
        acc[mt][nt] = __builtin_amdgcn_mfma_f32_16x16x32_bf16(                 \
            af[mt], bfr[nt], acc[mt][nt], 0, 0, 0);                            \
  }                                                                            \
} while(0)

__global__ __launch_bounds__(256, 2) void k2d(const bf16* __restrict__ dt,
    const bf16* __restrict__ w1t, const float* __restrict__ b1,
    const float* __restrict__ w2, float* __restrict__ outs)
{
  int n0 = blockIdx.x*256;         // BN=256 (divides TLEN)
  int m0 = blockIdx.y;             // 0..3: co quarter
  int b  = n0 / TLEN;
  int t0 = n0 % TLEN;
  int tid  = threadIdx.x;          // 0..255
  int lane = tid & 63;
  int wN   = tid >> 6;             // wave 0..3 = 64-col n group
  int ln15 = lane & 15, quad = lane >> 4;

  __shared__ bf16 Ws[2][3*64*40];  // 30,720 B
  __shared__ bf16 Dt[2][258*32];   // 33,024 B
  __shared__ float Ss[256];

  f32x4 acc[4][4];
  #pragma unroll
  for (int i=0;i<4;++i)
    #pragma unroll
    for (int j=0;j<4;++j) acc[i][j] = (f32x4){0.f,0.f,0.f,0.f};

  // prologue: stage ch=0 into buffer 0
  DMA_W2(0, 0);
  DMA_D2(0, 0);
  __syncthreads();                 // drains DMA (vmcnt)

  for (int ch=0; ch<16; ++ch) {
    int cur = ch & 1;
    int nxt = cur ^ 1;
    if (ch < 15) {                 // issue next chunk early (uniform branch)
      DMA_W2(nxt, ch+1);
      DMA_D2(nxt, ch+1);
    }
    COMPUTE2(cur);                 // ds_read + MFMA hide the in-flight DMA
    __syncthreads();               // one barrier/iter; drains nxt DMA
  }

  // epilogue: strength[n] += sum_{co in quarter} relu(H[co][n]+b1[co])*w2[co]
  float part[4] = {0.f,0.f,0.f,0.f};
  #pragma unroll
  for (int mt=0;mt<4;++mt) {
    #pragma unroll
    for (int rr=0;rr<4;++rr) {
      int row = m0*64 + mt*16 + quad*4 + rr;
      float bias = b1[row];
      float wv   = w2[row];
      #pragma unroll
      for (int nt=0;nt<4;++nt) {
        float h = acc[mt][nt][rr] + bias;
        h = fmaxf(h, 0.f);
        part[nt] = fmaf(h, wv, part[nt]);
      }
    }
  }
  Ss[tid] = 0.f;
  __syncthreads();
  #pragma unroll
  for (int nt=0;nt<4;++nt)
    atomicAdd(&Ss[wN*64 + nt*16 + ln15], part[nt]);
  __syncthreads();
  atomicAdd(&outs[n0 + tid], Ss[tid]);
}

// ---------------------------------------------------------------------------
// k2r: R5 fallback (register-staged def) -- used only if ws too small for
// dtile. Identical to the R5-measured 51.9us kernel.
// ---------------------------------------------------------------------------
#define DMA_WSR(dst, ch_) do {                                                 \
  const char* gs = (const char*)(w1t + (size_t)((ch_)*4 + m0)*7680);           \
  char* ld = (char*)&Ws[dst][0];                                               \
  for (int of = tid*16; of < 15360; of += 4096) {                              \
    __builtin_amdgcn_global_load_lds(                                          \
        (const __attribute__((address_space(1))) unsigned int*)(gs + of),      \
        (__attribute__((address_space(3))) unsigned int*)(ld + of), 16, 0, 0); \
  }                                                                            \
} while(0)

#define LOAD_DTR(ch_) do {                                                     \
  const float* dpb = def + ((size_t)b*CHN + (ch_)*32 + g*8)*TLEN;              \
  _Pragma("unroll")                                                            \
  for (int s=0;s<4;++s) {                                                      \
    int t = t0 - 1 + tl + s*64;                                                \
    _Pragma("unroll")                                                          \
    for (int j=0;j<8;++j)                                                      \
      rg[s][j] = (t>=0 && t<TLEN) ? dpb[(size_t)j*TLEN + t] : 0.f;             \
  }                                                                            \
  if (tl < 2) {                                                                \
    int t = t0 - 1 + 256 + tl;                                                 \
    _Pragma("unroll")                                                          \
    for (int j=0;j<8;++j)                                                      \
      rt[j] = (t<TLEN) ? dpb[(size_t)j*TLEN + t] : 0.f;                        \
  }                                                                            \
} while(0)

#define WRITE_DTR(dst) do {                                                    \
  _Pragma("unroll")                                                            \
  for (int s=0;s<4;++s) {                                                      \
    bf16x8 v;                                                                  \
    _Pragma("unroll")                                                          \
    for (int j=0;j<8;++j) { union{bf16 h; short u;} cv;                        \
      cv.h = __float2bfloat16(rg[s][j]); v[j] = cv.u; }                        \
    *(bf16x8*)((char*)&Dt[dst][0] + (tl + s*64)*80 + g*16) = v;                \
  }                                                                            \
  if (tl < 2) {                                                                \
    bf16x8 v;                                                                  \
    _Pragma("unroll")                                                          \
    for (int j=0;j<8;++j) { union{bf16 h; short u;} cv;                        \
      cv.h = __float2bfloat16(rt[j]); v[j] = cv.u; }                           \
    *(bf16x8*)((char*)&Dt[dst][0] + (256 + tl)*80 + g*16) = v;                 \
  }                                                                            \
} while(0)

#define COMPUTER(cur) do {                                                     \
  _Pragma("unroll")                                                            \
  for (int r=0;r<3;++r) {                                                      \
    bf16x8 af[4], bfr[4];                                                      \
    _Pragma("unroll")                                                          \
    for (int mt=0;mt<4;++mt)                                                   \
      af[mt] = *(const bf16x8*)&Ws[cur][(size_t)(r*64 + mt*16 + ln15)*40 + quad*8];\
    _Pragma("unroll")                                                          \
    for (int nt=0;nt<4;++nt)                                                   \
      bfr[nt] = *(const bf16x8*)&Dt[cur][(size_t)(wN*64 + nt*16 + ln15 + r)*40 + quad*8];\
    _Pragma("unroll")                                                          \
    for (int mt=0;mt<4;++mt)                                                   \
      _Pragma("unroll")                                                        \
      for (int nt=0;nt<4;++nt)                                                 \
        acc[mt][nt] = __builtin_amdgcn_mfma_f32_16x16x32_bf16(                 \
            af[mt], bfr[nt], acc[mt][nt], 0, 0, 0);                            \
  }                                                                            \
} while(0)

__global__ __launch_bounds__(256, 2) void k2r(const float* __restrict__ def,
    const bf16* __restrict__ w1t, const float* __restrict__ b1,
    const float* __restrict__ w2, float* __restrict__ outs)
{
  int n0 = blockIdx.x*256;
  int m0 = blockIdx.y;
  int b  = n0 / TLEN;
  int t0 = n0 % TLEN;
  int tid  = threadIdx.x;
  int lane = tid & 63;
  int wN   = tid >> 6;
  int ln15 = lane & 15, quad = lane >> 4;

  __shared__ bf16 Ws[2][3*64*40];
  __shared__ bf16 Dt[2][258*40];
  __shared__ float Ss[256];

  int g  = tid >> 6;
  int tl = tid & 63;

  f32x4 acc[4][4];
  #pragma unroll
  for (int i=0;i<4;++i)
    #pragma unroll
    for (int j=0;j<4;++j) acc[i][j] = (f32x4){0.f,0.f,0.f,0.f};

  float rg[4][8], rt[8];
  #pragma unroll
  for (int j=0;j<8;++j) rt[j] = 0.f;

  DMA_WSR(0, 0);
  LOAD_DTR(0);
  WRITE_DTR(0);
  __syncthreads();

  for (int ch=0; ch<16; ++ch) {
    int cur = ch & 1;
    int nxt = cur ^ 1;
    if (ch < 15) {
      DMA_WSR(nxt, ch+1);
      LOAD_DTR(ch+1);
    }
    COMPUTER(cur);
    if (ch < 15)
      WRITE_DTR(nxt);
    __syncthreads();
  }

  float part[4] = {0.f,0.f,0.f,0.f};
  #pragma unroll
  for (int mt=0;mt<4;++mt) {
    #pragma unroll
    for (int rr=0;rr<4;++rr) {
      int row = m0*64 + mt*16 + quad*4 + rr;
      float bias = b1[row];
      float wv   = w2[row];
      #pragma unroll
      for (int nt=0;nt<4;++nt) {
        float h = acc[mt][nt][rr] + bias;
        h = fmaxf(h, 0.f);
        part[nt] = fmaf(h, wv, part[nt]);
      }
    }
  }
  Ss[tid] = 0.f;
  __syncthreads();
  #pragma unroll
  for (int nt=0;nt<4;++nt)
    atomicAdd(&Ss[wN*64 + nt*16 + ln15], part[nt]);
  __syncthreads();
  atomicAdd(&outs[n0 + tid], Ss[tid]);
}

extern "C" void kernel_launch(void* const* d_in, const int* in_sizes, int n_in,
                              void* d_out, int out_size, void* d_ws, size_t ws_size,
                              hipStream_t stream) {
  const float* x  = (const float*)d_in[0];
  const float* ow = (const float*)d_in[1];
  const float* ob = (const float*)d_in[2];
  const float* mw = (const float*)d_in[3];
  const float* mb = (const float*)d_in[4];
  const float* wg = (const float*)d_in[5];
  const float* w1 = (const float*)d_in[6];
  const float* b1 = (const float*)d_in[7];
  const float* w2 = (const float*)d_in[8];
  const float* b2 = (const float*)d_in[9];

  float* out_def = (float*)d_out;
  float* out_str = out_def + (size_t)BATCH*CHN*TLEN;

  float2* samp = (float2*)d_ws;                                  // 1.31 MB
  bf16*   w1t  = (bf16*)((char*)d_ws + SAMP_BYTES);              // 983 KB
  float*  wpk  = (float*)((char*)d_ws + SAMP_BYTES + W1T_BYTES); // 64 KB

  size_t need = (size_t)SAMP_BYTES + W1T_BYTES + WPK_BYTES + DT_BYTES;
  bf16* dt = (ws_size >= need)
      ? (bf16*)((char*)d_ws + SAMP_BYTES + W1T_BYTES + WPK_BYTES)
      : nullptr;

  kPrep<<<dim3(W1T_ELEMS/256 + 256), 256, 0, stream>>>(
      w1, w1t, ow, mw, wpk, out_str, b2, dt);
  kS   <<<dim3(TLEN/64, BATCH), dim3(64,8), 0, stream>>>(x, wpk, ob, mb, samp);
  if (dt) {
    kDf<true> <<<dim3(TLEN/(2*BT), CHN/16, BATCH), 64, 0, stream>>>(
        x, wg, samp, out_def, dt);
    k2d<<<dim3(BATCH*TLEN/256, 4), 256, 0, stream>>>(dt, w1t, b1, w2, out_str);
  } else {
    kDf<false><<<dim3(TLEN/(2*BT), CHN/16, BATCH), 64, 0, stream>>>(
        x, wg, samp, out_def, nullptr);
    k2r<<<dim3(BATCH*TLEN/256, 4), 256, 0, stream>>>(out_def, w1t, b1, w2, out_str);
  }
}

// Round 10
// 208.930 us; speedup vs baseline: 1.0882x; 1.0882x over previous
//
#include <hip/hip_runtime.h>
#include <hip/hip_bf16.h>

#define CHN 512
#define TLEN 2048
#define KSZ 5
#define BATCH 16

typedef __hip_bfloat16 bf16;
typedef short bf16x8 __attribute__((ext_vector_type(8)));   // 8 bf16 (4 VGPRs)
typedef float f32x4  __attribute__((ext_vector_type(4)));

// ws layout:
//   samp : float2[B*T*5]  (pos, sig)       =  1,310,720 B
//   w1t  : bf16 [16][4][3][64][40]         =    983,040 B   (pre-tiled W1)
//   wpk  : float[512][32]                  =     65,536 B   (packed ow+mw)
//   dtile: bf16 [B][16][2050][32]          = 33,587,200 B   (bf16 def, k2-tiled)
//          row t+1 holds def[b][ch*32+col][t]; rows 0,2049 = zeros (halo)
#define SAMP_BYTES (BATCH*TLEN*KSZ*8)
#define W1T_ELEMS  (16*4*3*64*40)
#define W1T_BYTES  (W1T_ELEMS*2)
#define WPK_BYTES  65536
#define DT_ROWS    2050
#define DT_CHUNK   (DT_ROWS*32)                 // elems per (b,ch)
#define DT_BYTES   ((size_t)BATCH*16*DT_CHUNK*2)

// ---------------------------------------------------------------------------
// kPrep: fused kP (w1 retile) + kW (ow/mw pack) + kZ (outs = b2) +
//        dtile halo-row zeroing. One dispatch.
// ---------------------------------------------------------------------------
__global__ __launch_bounds__(256) void kPrep(const float* __restrict__ w1,
    bf16* __restrict__ w1t, const float* __restrict__ ow,
    const float* __restrict__ mw, float* __restrict__ wpk,
    float* __restrict__ outs, const float* __restrict__ b2p,
    bf16* __restrict__ dt)
{
  int bx = blockIdx.x;
  int tidl = threadIdx.x;
  const int NP = W1T_ELEMS/256;                // 1920
  if (bx < NP) {
    // kP: w1 fp32 [co][ci][r] -> w1t bf16 [ch][q][r][row][40], co = q*64+row
    int idx  = bx*256 + tidl;                  // < 491520
    int c40  = idx % 40;
    int rest = idx / 40;
    int row  = rest & 63;
    int rr   = rest >> 6;          // (ch*4+q)*3 + r
    int r    = rr % 3;
    int cq   = rr / 3;             // ch*4 + q
    int q    = cq & 3;
    int ch   = cq >> 2;
    int co   = q*64 + row;
    float v = 0.f;
    if (c40 < 32) v = w1[(size_t)co*(CHN*3) + (ch*32 + c40)*3 + r];
    w1t[idx] = __float2bfloat16(v);
  } else if (bx < NP + 64) {
    // kW: pack ow/mw -> wpk[c][32]
    int idx = (bx - NP)*256 + tidl;            // < 16384
    int j = idx & 31, c = idx >> 5;
    float v = 0.f;
    if (j < 15)      { int o = j/3,  d = j - o*3;  v = ow[o*(CHN*3) + c*3 + d]; }
    else if (j < 30) { int jj = j-15; int o = jj/3, d = jj - o*3;
                       v = mw[o*(CHN*3) + c*3 + d]; }
    wpk[idx] = v;
  } else if (bx < NP + 192) {
    // kZ: outs = b2 (k2 blocks atomically accumulate on top)
    outs[(bx - NP - 64)*256 + tidl] = b2p[0];
  } else if (dt) {
    // zero dtile halo rows 0 (t=-1) and 2049 (t=2048), all 256 (b,ch) chunks
    int z = (bx - NP - 192)*256 + tidl;        // < 16384
    int chunk = z >> 6;                        // 0..255
    int row   = ((z >> 5) & 1) ? (DT_ROWS-1) : 0;
    int col   = z & 31;
    dt[(size_t)chunk*DT_CHUNK + row*32 + col] = __float2bfloat16(0.f);
  }
}

// ---------------------------------------------------------------------------
// kS: offset conv (out 0..4) + modulator conv (+sigmoid) -> sampling params.
// grid (TLEN/64, B), block (64 t, 8 cg). Each thread reduces 64 channels.
// samp[b,t,k] = (pos, sig); kDf re-derives base/wf/wc (bitwise-identical).
// ---------------------------------------------------------------------------
__global__ __launch_bounds__(512) void kS(const float* __restrict__ x,
    const float* __restrict__ wpk, const float* __restrict__ ob,
    const float* __restrict__ mb, float2* __restrict__ samp)
{
  int b  = blockIdx.y;
  int t0 = blockIdx.x*64;
  int tx = threadIdx.x;
  int cg = threadIdx.y;            // 0..7 (wave-uniform: wave = one tx row)
  int t  = t0 + tx;

  __shared__ float red[8][64][10];

  float acc[10];
  #pragma unroll
  for (int i=0;i<10;++i) acc[i]=0.f;
  const float* xb = x + (size_t)b*CHN*TLEN;
  int c0 = cg*64;
  #pragma unroll 4
  for (int c=c0;c<c0+64;++c) {
    int cu = __builtin_amdgcn_readfirstlane(c);
    const float* wp = wpk + cu*32;             // scalar -> s_load_dwordx8
    const float* xr = xb + (size_t)cu*TLEN;
    float xm = (t>0)      ? xr[t-1] : 0.f;
    float xc = xr[t];
    float xp = (t<TLEN-1) ? xr[t+1] : 0.f;
    #pragma unroll
    for (int o=0;o<5;++o) {
      acc[o]   = fmaf(xm, wp[o*3+0],    acc[o]);
      acc[o]   = fmaf(xc, wp[o*3+1],    acc[o]);
      acc[o]   = fmaf(xp, wp[o*3+2],    acc[o]);
      acc[5+o] = fmaf(xm, wp[15+o*3+0], acc[5+o]);
      acc[5+o] = fmaf(xc, wp[15+o*3+1], acc[5+o]);
      acc[5+o] = fmaf(xp, wp[15+o*3+2], acc[5+o]);
    }
  }
  #pragma unroll
  for (int i=0;i<10;++i) red[cg][tx][i] = acc[i];
  __syncthreads();
  for (int s=4;s>0;s>>=1) {
    if (cg < s) {
      #pragma unroll
      for (int i=0;i<10;++i) red[cg][tx][i] += red[cg+s][tx][i];
    }
    __syncthreads();
  }
  if (cg==0) {
    #pragma unroll
    for (int k=0;k<KSZ;++k) {
      float off = red[0][tx][k]   + ob[k];
      float mv  = red[0][tx][5+k] + mb[k];
      float sig = 1.f/(1.f + expf(-mv));
      float pos = (float)(t + k - 2) + off;
      pos = fminf(fmaxf(pos, 0.f), (float)(TLEN-1));
      samp[((size_t)b*TLEN + t)*KSZ + k] = make_float2(pos, sig);
    }
  }
}

// ---------------------------------------------------------------------------
// kDf: deformable sampling w/ diagonal weight — wave-synchronous, NO barrier.
// (R7-measured configuration: 41.3us, VGPR 80 — best of R6-R9 variants.
//  R8 2-wave packing: null; R9 2-tile counted-vmcnt: VGPR 140, occupancy
//  9%, 60us — intra-wave depth trades against the TLP doing the hiding.)
// grid (T/128, C/16, B), block = ONE wave (64 thr). The wave stages its own
// 16 c-rows of x into LDS (10.25 KB), fences with a per-wave vmcnt(0), and
// serves all gathers from LDS. Sampling params read directly from sampg
// (L2/L3-hot). Thread owns t = {t0+tx, t0+64+tx} x 16 c-rows.
// If WDT, packs 16 ci-contiguous bf16 per t and stores 32 B to dtile.
// Wave-uniform fallback to global gathers if any base escapes the halo.
// ---------------------------------------------------------------------------
#define BT   128
#define HALO 16
#define XLEN 160   // BT + 2*HALO

template<bool WDT>
__global__ __launch_bounds__(64) void kDf(const float* __restrict__ x,
    const float* __restrict__ wgt, const float2* __restrict__ sampg,
    float* __restrict__ out, bf16* __restrict__ dt)
{
  int b  = blockIdx.z;
  int c0 = blockIdx.y*16;
  int t0 = blockIdx.x*BT;
  int tx = threadIdx.x;

  __shared__ float xs[16*XLEN];     // 10,240 B

  int lo = min(max(t0 - HALO, 0), TLEN - XLEN);   // window always in-bounds
                                                  // (and 16B-aligned: lo%16==0)

  // --- DMA own x tile: 16 rows x 160 floats = 640 float4 chunks, 10/lane.
  const float* xb = x + (size_t)b*CHN*TLEN;
  #pragma unroll
  for (int it = 0; it < 10; ++it) {
    int idx = tx + it*64;
    int c  = idx / 40;             // local c row
    int c4 = idx - c*40;           // float4 within row
    const float* src = xb + (size_t)(c0 + c)*TLEN + lo + c4*4;
    __builtin_amdgcn_global_load_lds(
        (const __attribute__((address_space(1))) unsigned int*)src,
        (__attribute__((address_space(3))) unsigned int*)&xs[idx*4],
        16, 0, 0);
  }

  // --- sampling params straight from global (covers DMA latency with VALU)
  int   bl[2][KSZ];
  float wf[2][KSZ], wc[2][KSZ];
  bool ok = true;
  #pragma unroll
  for (int j=0;j<2;++j)
    #pragma unroll
    for (int k=0;k<KSZ;++k) {
      float2 s = sampg[((size_t)b*TLEN + t0 + j*64 + tx)*KSZ + k];
      float pos = s.x, sig = s.y;
      float pf = floorf(pos), pc = ceilf(pos);
      int base = min((int)pf, TLEN-2);
      wf[j][k] = (pc - pos)*sig;     // ref quirk: pos integral -> wf=wc=0
      wc[j][k] = (pos - pf)*sig;
      int bloc = base - lo;
      bl[j][k] = bloc;
      ok = ok && (bloc >= 0) && (bloc <= XLEN-2);
    }
  int fast = __all((int)ok);        // wave-uniform branch

  // fence: own-wave DMA -> LDS reads (no barrier; LDS is private to wave)
  asm volatile("s_waitcnt vmcnt(0)" ::: "memory");
  __builtin_amdgcn_sched_barrier(0);

  unsigned pk0[8], pk1[8];
  if (fast) {
    #pragma unroll
    for (int i=0;i<16;++i) {         // FULL unroll: pk[] statically indexed
      int cu = __builtin_amdgcn_readfirstlane(c0 + i);
      const float* wd = wgt + (size_t)cu*(CHN*KSZ) + (size_t)cu*KSZ;  // diag
      float w0 = wd[0], w1v = wd[1], w2v = wd[2], w3 = wd[3], w4 = wd[4];
      const float* xr = xs + i*XLEN;
      float o0, o1;
      {
        float a = 0.f;
        a = fmaf(fmaf(xr[bl[0][0]+1], wc[0][0], xr[bl[0][0]]*wf[0][0]), w0,  a);
        a = fmaf(fmaf(xr[bl[0][1]+1], wc[0][1], xr[bl[0][1]]*wf[0][1]), w1v, a);
        a = fmaf(fmaf(xr[bl[0][2]+1], wc[0][2], xr[bl[0][2]]*wf[0][2]), w2v, a);
        a = fmaf(fmaf(xr[bl[0][3]+1], wc[0][3], xr[bl[0][3]]*wf[0][3]), w3,  a);
        a = fmaf(fmaf(xr[bl[0][4]+1], wc[0][4], xr[bl[0][4]]*wf[0][4]), w4,  a);
        o0 = a;
      }
      {
        float a = 0.f;
        a = fmaf(fmaf(xr[bl[1][0]+1], wc[1][0], xr[bl[1][0]]*wf[1][0]), w0,  a);
        a = fmaf(fmaf(xr[bl[1][1]+1], wc[1][1], xr[bl[1][1]]*wf[1][1]), w1v, a);
        a = fmaf(fmaf(xr[bl[1][2]+1], wc[1][2], xr[bl[1][2]]*wf[1][2]), w2v, a);
        a = fmaf(fmaf(xr[bl[1][3]+1], wc[1][3], xr[bl[1][3]]*wf[1][3]), w3,  a);
        a = fmaf(fmaf(xr[bl[1][4]+1], wc[1][4], xr[bl[1][4]]*wf[1][4]), w4,  a);
        o1 = a;
      }
      size_t op = ((size_t)b*CHN + cu)*TLEN + t0 + tx;
      out[op]      = o0;
      out[op + 64] = o1;
      if (WDT) {
        union { bf16 h; unsigned short u; } cv0, cv1;
        cv0.h = __float2bfloat16(o0);
        cv1.h = __float2bfloat16(o1);
        if (i & 1) { pk0[i>>1] |= (unsigned)cv0.u << 16;
                     pk1[i>>1] |= (unsigned)cv1.u << 16; }
        else       { pk0[i>>1]  = cv0.u;  pk1[i>>1]  = cv1.u; }
      }
    }
  } else {
    // slow path (never taken with bench weights): global gathers, same math
    #pragma unroll
    for (int i=0;i<16;++i) {
      int cu = __builtin_amdgcn_readfirstlane(c0 + i);
      const float* wd = wgt + (size_t)cu*(CHN*KSZ) + (size_t)cu*KSZ;
      float wk0 = wd[0], wk1 = wd[1], wk2 = wd[2], wk3 = wd[3], wk4 = wd[4];
      const float* xr = xb + (size_t)cu*TLEN + lo;   // xr[bl] == x[base]
      float o[2];
      #pragma unroll
      for (int j=0;j<2;++j) {
        float a = 0.f;
        a = fmaf(fmaf(xr[bl[j][0]+1], wc[j][0], xr[bl[j][0]]*wf[j][0]), wk0, a);
        a = fmaf(fmaf(xr[bl[j][1]+1], wc[j][1], xr[bl[j][1]]*wf[j][1]), wk1, a);
        a = fmaf(fmaf(xr[bl[j][2]+1], wc[j][2], xr[bl[j][2]]*wf[j][2]), wk2, a);
        a = fmaf(fmaf(xr[bl[j][3]+1], wc[j][3], xr[bl[j][3]]*wf[j][3]), wk3, a);
        a = fmaf(fmaf(xr[bl[j][4]+1], wc[j][4], xr[bl[j][4]]*wf[j][4]), wk4, a);
        o[j] = a;
      }
      size_t op = ((size_t)b*CHN + cu)*TLEN + t0 + tx;
      out[op]      = o[0];
      out[op + 64] = o[1];
      if (WDT) {
        union { bf16 h; unsigned short u; } cv0, cv1;
        cv0.h = __float2bfloat16(o[0]);
        cv1.h = __float2bfloat16(o[1]);
        if (i & 1) { pk0[i>>1] |= (unsigned)cv0.u << 16;
                     pk1[i>>1] |= (unsigned)cv1.u << 16; }
        else       { pk0[i>>1]  = cv0.u;  pk1[i>>1]  = cv1.u; }
      }
    }
  }

  if (WDT) {
    // thread's 16 bf16 are ci-contiguous: chunk (b,ch), row t+1, col half
    int ch   = blockIdx.y >> 1;
    int colb = (blockIdx.y & 1)*16;
    bf16* p0 = dt + (size_t)(b*16 + ch)*DT_CHUNK
                  + (size_t)(t0 + tx + 1)*32 + colb;
    *(uint4*)p0       = make_uint4(pk0[0], pk0[1], pk0[2], pk0[3]);
    *((uint4*)p0 + 1) = make_uint4(pk0[4], pk0[5], pk0[6], pk0[7]);
    bf16* p1 = p0 + 64*32;
    *(uint4*)p1       = make_uint4(pk1[0], pk1[1], pk1[2], pk1[3]);
    *((uint4*)p1 + 1) = make_uint4(pk1[4], pk1[5], pk1[6], pk1[7]);
  }
}

// ---------------------------------------------------------------------------
// k2d: fused rp1(conv3, 512->256)+ReLU+rp2(256->1)+bias, bf16 MFMA.
// BOTH operands staged by pure global_load_lds DMA (Ws from w1t, Dt from
// dtile -- no loads/cvt/ds_write in the loop). Double-buffered, 2 blocks/CU
// (LDS 64.8 KB). BM=64 (co-quarter, grid y=4), BN=256, 256 thr (4 waves).
// Per iter: issue next Ws+Dt DMA -> COMPUTE(cur) hides DMA latency ->
// single barrier. Partial co-sums atomicAdd into outs (pre-set to b2).
// ---------------------------------------------------------------------------
#define DMA_W2(dst, ch_) do {                                                  \
  const char* gs = (const char*)(w1t + (size_t)((ch_)*4 + m0)*7680);           \
  char* ld = (char*)&Ws[dst][0];                                               \
  for (int of = tid*16; of < 15360; of += 4096) {                              \
    __builtin_amdgcn_global_load_lds(                                          \
        (const __attribute__((address_space(1))) unsigned int*)(gs + of),      \
        (__attribute__((address_space(3))) unsigned int*)(ld + of), 16, 0, 0); \
  }                                                                            \
} while(0)

#define DMA_D2(dst, ch_) do {                                                  \
  const char* gs = (const char*)(dt + (size_t)(b*16 + (ch_))*DT_CHUNK          \
                                    + (size_t)t0*32);                          \
  char* ld = (char*)&Dt[dst][0];                                               \
  for (int of = tid*16; of < 16512; of += 4096) {                              \
    __builtin_amdgcn_global_load_lds(                                          \
        (const __attribute__((address_space(1))) unsigned int*)(gs + of),      \
        (__attribute__((address_space(3))) unsigned int*)(ld + of), 16, 0, 0); \
  }                                                                            \
} while(0)

#define COMPUTE2(cur) do {                                                     \
  _Pragma("unroll")                                                            \
  for (int r=0;r<3;++r) {                                                      \
    bf16x8 af[4], bfr[4];                                                      \
    _Pragma("unroll")                                                          \
    for (int mt=0;mt<4;++mt)                                                   \
      af[mt] = *(const bf16x8*)&Ws[cur][(size_t)(r*64 + mt*16 + ln15)*40 + quad*8];\
    _Pragma("unroll")                                                          \
    for (int nt=0;nt<4;++nt)                                                   \
      bfr[nt] = *(const bf16x8*)&Dt[cur][(size_t)(wN*64 + nt*16 + ln15 + r)*32 + quad*8];\
    _Pragma("unroll")                                                          \
    for (int mt=0;mt<4;++mt)                                                   \
      _Pragma("unroll")                                                        \
      for (int nt=0;nt<4;++nt)                                                 \
        acc[mt][nt] = __builtin_amdgcn_mfma_f32_16x16x32_bf16(                 \
            af[mt], bfr[nt], acc[mt][nt], 0, 0, 0);                            \
  }                                                                            \
} while(0)

__global__ __launch_bounds__(256, 2) void k2d(const bf16* __restrict__ dt,
    const bf16* __restrict__ w1t, const float* __restrict__ b1,
    const float* __restrict__ w2, float* __restrict__ outs)
{
  int n0 = blockIdx.x*256;         // BN=256 (divides TLEN)
  int m0 = blockIdx.y;             // 0..3: co quarter
  int b  = n0 / TLEN;
  int t0 = n0 % TLEN;
  int tid  = threadIdx.x;          // 0..255
  int lane = tid & 63;
  int wN   = tid >> 6;             // wave 0..3 = 64-col n group
  int ln15 = lane & 15, quad = lane >> 4;

  __shared__ bf16 Ws[2][3*64*40];  // 30,720 B
  __shared__ bf16 Dt[2][258*32];   // 33,024 B
  __shared__ float Ss[256];

  f32x4 acc[4][4];
  #pragma unroll
  for (int i=0;i<4;++i)
    #pragma unroll
    for (int j=0;j<4;++j) acc[i][j] = (f32x4){0.f,0.f,0.f,0.f};

  // prologue: stage ch=0 into buffer 0
  DMA_W2(0, 0);
  DMA_D2(0, 0);
  __syncthreads();                 // drains DMA (vmcnt)

  for (int ch=0; ch<16; ++ch) {
    int cur = ch & 1;
    int nxt = cur ^ 1;
    if (ch < 15) {                 // issue next chunk early (uniform branch)
      DMA_W2(nxt, ch+1);
      DMA_D2(nxt, ch+1);
    }
    COMPUTE2(cur);                 // ds_read + MFMA hide the in-flight DMA
    __syncthreads();               // one barrier/iter; drains nxt DMA
  }

  // epilogue: strength[n] += sum_{co in quarter} relu(H[co][n]+b1[co])*w2[co]
  float part[4] = {0.f,0.f,0.f,0.f};
  #pragma unroll
  for (int mt=0;mt<4;++mt) {
    #pragma unroll
    for (int rr=0;rr<4;++rr) {
      int row = m0*64 + mt*16 + quad*4 + rr;
      float bias = b1[row];
      float wv   = w2[row];
      #pragma unroll
      for (int nt=0;nt<4;++nt) {
        float h = acc[mt][nt][rr] + bias;
        h = fmaxf(h, 0.f);
        part[nt] = fmaf(h, wv, part[nt]);
      }
    }
  }
  Ss[tid] = 0.f;
  __syncthreads();
  #pragma unroll
  for (int nt=0;nt<4;++nt)
    atomicAdd(&Ss[wN*64 + nt*16 + ln15], part[nt]);
  __syncthreads();
  atomicAdd(&outs[n0 + tid], Ss[tid]);
}

// ---------------------------------------------------------------------------
// k2r: R5 fallback (register-staged def) -- used only if ws too small for
// dtile. Identical to the R5-measured 51.9us kernel.
// ---------------------------------------------------------------------------
#define DMA_WSR(dst, ch_) do {                                                 \
  const char* gs = (const char*)(w1t + (size_t)((ch_)*4 + m0)*7680);           \
  char* ld = (char*)&Ws[dst][0];                                               \
  for (int of = tid*16; of < 15360; of += 4096) {                              \
    __builtin_amdgcn_global_load_lds(                                          \
        (const __attribute__((address_space(1))) unsigned int*)(gs + of),      \
        (__attribute__((address_space(3))) unsigned int*)(ld + of), 16, 0, 0); \
  }                                                                            \
} while(0)

#define LOAD_DTR(ch_) do {                                                     \
  const float* dpb = def + ((size_t)b*CHN + (ch_)*32 + g*8)*TLEN;              \
  _Pragma("unroll")                                                            \
  for (int s=0;s<4;++s) {                                                      \
    int t = t0 - 1 + tl + s*64;                                                \
    _Pragma("unroll")                                                          \
    for (int j=0;j<8;++j)                                                      \
      rg[s][j] = (t>=0 && t<TLEN) ? dpb[(size_t)j*TLEN + t] : 0.f;             \
  }                                                                            \
  if (tl < 2) {                                                                \
    int t = t0 - 1 + 256 + tl;                                                 \
    _Pragma("unroll")                                                          \
    for (int j=0;j<8;++j)                                                      \
      rt[j] = (t<TLEN) ? dpb[(size_t)j*TLEN + t] : 0.f;                        \
  }                                                                            \
} while(0)

#define WRITE_DTR(dst) do {                                                    \
  _Pragma("unroll")                                                            \
  for (int s=0;s<4;++s) {                                                      \
    bf16x8 v;                                                                  \
    _Pragma("unroll")                                                          \
    for (int j=0;j<8;++j) { union{bf16 h; short u;} cv;                        \
      cv.h = __float2bfloat16(rg[s][j]); v[j] = cv.u; }                        \
    *(bf16x8*)((char*)&Dt[dst][0] + (tl + s*64)*80 + g*16) = v;                \
  }                                                                            \
  if (tl < 2) {                                                                \
    bf16x8 v;                                                                  \
    _Pragma("unroll")                                                          \
    for (int j=0;j<8;++j) { union{bf16 h; short u;} cv;                        \
      cv.h = __float2bfloat16(rt[j]); v[j] = cv.u; }                           \
    *(bf16x8*)((char*)&Dt[dst][0] + (256 + tl)*80 + g*16) = v;                 \
  }                                                                            \
} while(0)

#define COMPUTER(cur) do {                                                     \
  _Pragma("unroll")                                                            \
  for (int r=0;r<3;++r) {                                                      \
    bf16x8 af[4], bfr[4];                                                      \
    _Pragma("unroll")                                                          \
    for (int mt=0;mt<4;++mt)                                                   \
      af[mt] = *(const bf16x8*)&Ws[cur][(size_t)(r*64 + mt*16 + ln15)*40 + quad*8];\
    _Pragma("unroll")                                                          \
    for (int nt=0;nt<4;++nt)                                                   \
      bfr[nt] = *(const bf16x8*)&Dt[cur][(size_t)(wN*64 + nt*16 + ln15 + r)*40 + quad*8];\
    _Pragma("unroll")                                                          \
    for (int mt=0;mt<4;++mt)                                                   \
      _Pragma("unroll")                                                        \
      for (int nt=0;nt<4;++nt)                                                 \
        acc[mt][nt] = __builtin_amdgcn_mfma_f32_16x16x32_bf16(                 \
            af[mt], bfr[nt], acc[mt][nt], 0, 0, 0);                            \
  }                                                                            \
} while(0)

__global__ __launch_bounds__(256, 2) void k2r(const float* __restrict__ def,
    const bf16* __restrict__ w1t, const float* __restrict__ b1,
    const float* __restrict__ w2, float* __restrict__ outs)
{
  int n0 = blockIdx.x*256;
  int m0 = blockIdx.y;
  int b  = n0 / TLEN;
  int t0 = n0 % TLEN;
  int tid  = threadIdx.x;
  int lane = tid & 63;
  int wN   = tid >> 6;
  int ln15 = lane & 15, quad = lane >> 4;

  __shared__ bf16 Ws[2][3*64*40];
  __shared__ bf16 Dt[2][258*40];
  __shared__ float Ss[256];

  int g  = tid >> 6;
  int tl = tid & 63;

  f32x4 acc[4][4];
  #pragma unroll
  for (int i=0;i<4;++i)
    #pragma unroll
    for (int j=0;j<4;++j) acc[i][j] = (f32x4){0.f,0.f,0.f,0.f};

  float rg[4][8], rt[8];
  #pragma unroll
  for (int j=0;j<8;++j) rt[j] = 0.f;

  DMA_WSR(0, 0);
  LOAD_DTR(0);
  WRITE_DTR(0);
  __syncthreads();

  for (int ch=0; ch<16; ++ch) {
    int cur = ch & 1;
    int nxt = cur ^ 1;
    if (ch < 15) {
      DMA_WSR(nxt, ch+1);
      LOAD_DTR(ch+1);
    }
    COMPUTER(cur);
    if (ch < 15)
      WRITE_DTR(nxt);
    __syncthreads();
  }

  float part[4] = {0.f,0.f,0.f,0.f};
  #pragma unroll
  for (int mt=0;mt<4;++mt) {
    #pragma unroll
    for (int rr=0;rr<4;++rr) {
      int row = m0*64 + mt*16 + quad*4 + rr;
      float bias = b1[row];
      float wv   = w2[row];
      #pragma unroll
      for (int nt=0;nt<4;++nt) {
        float h = acc[mt][nt][rr] + bias;
        h = fmaxf(h, 0.f);
        part[nt] = fmaf(h, wv, part[nt]);
      }
    }
  }
  Ss[tid] = 0.f;
  __syncthreads();
  #pragma unroll
  for (int nt=0;nt<4;++nt)
    atomicAdd(&Ss[wN*64 + nt*16 + ln15], part[nt]);
  __syncthreads();
  atomicAdd(&outs[n0 + tid], Ss[tid]);
}

extern "C" void kernel_launch(void* const* d_in, const int* in_sizes, int n_in,
                              void* d_out, int out_size, void* d_ws, size_t ws_size,
                              hipStream_t stream) {
  const float* x  = (const float*)d_in[0];
  const float* ow = (const float*)d_in[1];
  const float* ob = (const float*)d_in[2];
  const float* mw = (const float*)d_in[3];
  const float* mb = (const float*)d_in[4];
  const float* wg = (const float*)d_in[5];
  const float* w1 = (const float*)d_in[6];
  const float* b1 = (const float*)d_in[7];
  const float* w2 = (const float*)d_in[8];
  const float* b2 = (const float*)d_in[9];

  float* out_def = (float*)d_out;
  float* out_str = out_def + (size_t)BATCH*CHN*TLEN;

  float2* samp = (float2*)d_ws;                                  // 1.31 MB
  bf16*   w1t  = (bf16*)((char*)d_ws + SAMP_BYTES);              // 983 KB
  float*  wpk  = (float*)((char*)d_ws + SAMP_BYTES + W1T_BYTES); // 64 KB

  size_t need = (size_t)SAMP_BYTES + W1T_BYTES + WPK_BYTES + DT_BYTES;
  bf16* dt = (ws_size >= need)
      ? (bf16*)((char*)d_ws + SAMP_BYTES + W1T_BYTES + WPK_BYTES)
      : nullptr;

  kPrep<<<dim3(W1T_ELEMS/256 + 256), 256, 0, stream>>>(
      w1, w1t, ow, mw, wpk, out_str, b2, dt);
  kS   <<<dim3(TLEN/64, BATCH), dim3(64,8), 0, stream>>>(x, wpk, ob, mb, samp);
  if (dt) {
    kDf<true> <<<dim3(TLEN/BT, CHN/16, BATCH), 64, 0, stream>>>(
        x, wg, samp, out_def, dt);
    k2d<<<dim3(BATCH*TLEN/256, 4), 256, 0, stream>>>(dt, w1t, b1, w2, out_str);
  } else {
    kDf<false><<<dim3(TLEN/BT, CHN/16, BATCH), 64, 0, stream>>>(
        x, wg, samp, out_def, nullptr);
    k2r<<<dim3(BATCH*TLEN/256, 4), 256, 0, stream>>>(out_def, w1t, b1, w2, out_str);
  }
}